// Round 11
// baseline (352.149 us; speedup 1.0000x reference)
//
#include <hip/hip_runtime.h>
#include <hip/hip_bf16.h>
#include <stdint.h>

// Problem dims
#define NE 8
#define NT 1024
#define NH 2048
#define NI 1408
#define NI2 (2 * NI)  // 2816

typedef __attribute__((ext_vector_type(8))) short          bf16x8;
typedef __attribute__((ext_vector_type(8))) unsigned short u16x8;
typedef __attribute__((ext_vector_type(4))) float          f32x4;

__device__ __forceinline__ unsigned short f2bf(float f) {
  union { float f; uint32_t u; } v; v.f = f;
  uint32_t u = v.u;
  return (unsigned short)((u + 0x7FFFu + ((u >> 16) & 1u)) >> 16);  // RNE
}

// ---------------------------------------------------------------------------
// Fragment-tile layout (bf16): tensor [rows][K] stored as
//   [K/32 ktile][rows/16 rtile][tile of 512 elems]
// where within a tile, elem (row r in 0..15, k in 0..31) sits at
//   off = ((k>>3)&3)*128 + (r&15)*8 + (k&7)   (elems)
// so MFMA lane l's bf16x8 fragment (row=l&15, k=(l>>4)*8..+8) is the 16B at
// byte offset l*16 — one coalesced global_load_dwordx4 per wave per fragment.
// ---------------------------------------------------------------------------

// x: fp32 [E][NT][NH] -> frag tiles [E][NH/32][NT/16][512]
__global__ __launch_bounds__(256) void cvt_frag(const float* __restrict__ src,
                                                unsigned short* __restrict__ dst) {
  const int n8 = NE * NT * NH / 8;
  int i = blockIdx.x * blockDim.x + threadIdx.x;
  const int stride = gridDim.x * blockDim.x;
  for (; i < n8; i += stride) {
    const int k8 = i & (NH / 8 - 1);          // 0..255
    const int t  = (i >> 8) & (NT - 1);
    const int e  = i >> 18;
    const float4 f0 = ((const float4*)src)[i * 2];
    const float4 f1 = ((const float4*)src)[i * 2 + 1];
    u16x8 o;
    o[0] = f2bf(f0.x); o[1] = f2bf(f0.y); o[2] = f2bf(f0.z); o[3] = f2bf(f0.w);
    o[4] = f2bf(f1.x); o[5] = f2bf(f1.y); o[6] = f2bf(f1.z); o[7] = f2bf(f1.w);
    const int kt = k8 >> 2;
    const int kb = k8 & 3;
    const size_t off = (((size_t)e * (NH / 32) + kt) * (NT / 16) + (t >> 4)) * 512
                     + kb * 128 + (t & 15) * 8;
    *(u16x8*)(dst + off) = o;
  }
}

// Transpose + cvt: src [E][R][C] f32 (R = K dim) -> frag tiles
// [E][R/32][CT16][512] with output row index ro mapped from c
// (ilv: 16-col gate/up interleave).
__global__ __launch_bounds__(256) void transpose_frag(
    const float* __restrict__ src, unsigned short* __restrict__ dst,
    int R, int C, int CT16, long estride, int ilv, int radd) {
  __shared__ float tile[64][65];
  const int e  = blockIdx.z;
  const int c0 = blockIdx.x * 64;
  const int r0 = blockIdx.y * 64;
  const float* s = src + (size_t)e * R * C;
  unsigned short* d = dst + (size_t)e * estride;
  const int tid = threadIdx.x;
  const int tr  = tid >> 4;
  const int tc  = (tid & 15) * 4;
  #pragma unroll
  for (int it = 0; it < 4; ++it) {
    const int r = it * 16 + tr;
    float4 v = *(const float4*)(s + (size_t)(r0 + r) * C + c0 + tc);
    tile[r][tc + 0] = v.x; tile[r][tc + 1] = v.y;
    tile[r][tc + 2] = v.z; tile[r][tc + 3] = v.w;
  }
  __syncthreads();
  const int oc = tid >> 2;         // 0..63 tile column (output row)
  const int rb = (tid & 3) * 16;   // k chunk base
  u16x8 o0, o1;
  #pragma unroll
  for (int j = 0; j < 8; ++j) {
    o0[j] = f2bf(tile[rb + j][oc]);
    o1[j] = f2bf(tile[rb + 8 + j][oc]);
  }
  const int c  = c0 + oc;
  const int ro = ilv ? ((((c >> 4) << 5) | (c & 15)) | radd) : c;
  const int k0 = r0 + rb;          // multiple of 16
  const size_t off = (((size_t)(k0 >> 5)) * CT16 + (ro >> 4)) * 512
                   + ((k0 & 31) >> 3) * 128 + (ro & 15) * 8;
  *(u16x8*)(d + off)       = o0;   // k0..k0+7
  *(u16x8*)(d + off + 128) = o1;   // k0+8..k0+15
}

// ---------------------------------------------------------------------------
// No-LDS, no-barrier GEMM: frags loaded directly from global in frag layout.
// BM=128 (1 M-slice), BN=256 (4 waves x 64 cols); wave tile 128x64, acc 8x4.
// 2-deep register pipeline (even/odd named sets); compiler emits counted
// vmcnt waits automatically. 8 independent waves/CU (2 blocks), no sync ->
// stalls decorrelate and the CU matrix pipe saturates on aggregate demand.
// A [E][KT][64][512]; B [E][KT][NBY*16][512].
// MODE 0: f32 out [E][NT][NBY*256] (row-major)
// MODE 1: silu-pair -> h frag tiles [E][NI/32][NT/16][512] (B g/u interleaved)
// ---------------------------------------------------------------------------
template <int NBY, int KDIM, int MODE>
__global__ __launch_bounds__(256, 2) void gemm_frag(
    const unsigned short* __restrict__ Ag,
    const unsigned short* __restrict__ Bg,
    void* __restrict__ outp) {
  constexpr int KT    = KDIM / 32;   // 64 or 44 (even)
  constexpr int AT    = NT / 16;     // 64 A row-tiles
  constexpr int BT    = NBY * 16;    // B row-tiles
  constexpr int CHUNK = NBY * 8;     // blocks per XCD = one expert

  const int flat = blockIdx.x;
  const int orig = (flat & 7) * CHUNK + (flat >> 3);
  const int e    = orig / CHUNK;
  const int r    = orig % CHUNK;
  const int bx   = r & 7;
  const int by   = r >> 3;

  const int bm  = bx * 128;

  const int tid  = threadIdx.x;
  const int lane = tid & 63;
  const int w    = tid >> 6;        // 0..3, N-slice

  // lane-adjusted fragment base pointers (elems)
  const unsigned short* pa =
      Ag + ((size_t)e * KT * AT + (bm >> 4)) * 512 + lane * 8;
  const unsigned short* pb =
      Bg + ((size_t)e * KT * BT + by * 16 + w * 4) * 512 + lane * 8;

  f32x4 acc[8][4];
  #pragma unroll
  for (int i = 0; i < 8; ++i)
    #pragma unroll
    for (int j = 0; j < 4; ++j) acc[i][j] = f32x4{0.f, 0.f, 0.f, 0.f};

  bf16x8 aE[8], bE[4], aO[8], bO[4];

  auto LD = [&](bf16x8 (&a)[8], bf16x8 (&b)[4], int t) {
    const bf16x8* A0 = (const bf16x8*)(pa + (size_t)t * AT * 512);
    const bf16x8* B0 = (const bf16x8*)(pb + (size_t)t * BT * 512);
    #pragma unroll
    for (int mi = 0; mi < 8; ++mi) a[mi] = A0[mi * 64];
    #pragma unroll
    for (int nj = 0; nj < 4; ++nj) b[nj] = B0[nj * 64];
  };
  auto FMA = [&](bf16x8 (&a)[8], bf16x8 (&b)[4]) {
    #pragma unroll
    for (int mi = 0; mi < 8; ++mi)
      #pragma unroll
      for (int nj = 0; nj < 4; ++nj)
        acc[mi][nj] = __builtin_amdgcn_mfma_f32_16x16x32_bf16(
            a[mi], b[nj], acc[mi][nj], 0, 0, 0);
  };

  LD(aE, bE, 0);
  int t = 0;
  #pragma unroll 1
  for (; t + 2 < KT; t += 2) {
    LD(aO, bO, t + 1);
    FMA(aE, bE);
    LD(aE, bE, t + 2);
    FMA(aO, bO);
  }
  LD(aO, bO, t + 1);
  FMA(aE, bE);
  FMA(aO, bO);

  const int crow = (lane >> 4) * 4;
  const int ccol = lane & 15;
  if constexpr (MODE == 0) {
    float* oe = (float*)outp + (size_t)e * NT * (NBY * 256);
    #pragma unroll
    for (int mi = 0; mi < 8; ++mi)
      #pragma unroll
      for (int nj = 0; nj < 4; ++nj)
        #pragma unroll
        for (int j = 0; j < 4; ++j) {
          const int row = bm + mi * 16 + crow + j;
          const int col = by * 256 + w * 64 + nj * 16 + ccol;
          oe[(size_t)row * (NBY * 256) + col] = acc[mi][nj][j];
        }
  } else {
    // silu-pair -> h frag tiles [E][NI/32][NT/16][512].
    // h col i = by*128 + w*32 + p*16 + ccol; h row t = bm + mi*16 + crow + j
    unsigned short* he = (unsigned short*)outp + (size_t)e * (NI / 32) * (NT / 16) * 512;
    const int itile = by * 4 + w;          // i>>5
    #pragma unroll
    for (int mi = 0; mi < 8; ++mi)
      #pragma unroll
      for (int p = 0; p < 2; ++p) {
        const int kb = p * 2 + (ccol >> 3);      // (i&31)>>3
        const int ic = ccol & 7;                 // i&7
        const size_t base = ((size_t)itile * (NT / 16) + ((bm >> 4) + mi)) * 512
                          + kb * 128 + (crow) * 8 + ic;
        #pragma unroll
        for (int j = 0; j < 4; ++j) {
          const float g = acc[mi][2 * p][j];
          const float u = acc[mi][2 * p + 1][j];
          const float sv = g / (1.0f + __expf(-g)) * u;
          he[base + j * 8] = f2bf(sv);
        }
      }
  }
}

// ---------------------------------------------------------------------------
extern "C" void kernel_launch(void* const* d_in, const int* in_sizes, int n_in,
                              void* d_out, int out_size, void* d_ws, size_t ws_size,
                              hipStream_t stream) {
  const float* x    = (const float*)d_in[0];  // [E][T][H]
  const float* gate = (const float*)d_in[1];  // [E][H][I]
  const float* up   = (const float*)d_in[2];  // [E][H][I]
  const float* down = (const float*)d_in[3];  // [E][I][H]
  float* out = (float*)d_out;                 // [E][T][H]

  // workspace (bf16 frag tiles):
  // x_bf [E][64][64][512], wcat [E][64][176][512] (g/u interleaved),
  // dT [E][44][128][512], hb [E][44][64][512]
  unsigned short* x_bf = (unsigned short*)d_ws;
  unsigned short* wcat = x_bf + (size_t)NE * NT * NH;
  unsigned short* dT   = wcat + (size_t)NE * NI2 * NH;
  unsigned short* hb   = dT   + (size_t)NE * NH * NI;

  cvt_frag<<<2048, 256, 0, stream>>>(x, x_bf);

  transpose_frag<<<dim3(NI / 64, NH / 64, NE), 256, 0, stream>>>(
      gate, wcat, NH, NI, NI2 / 16, (long)NI2 * NH, 1, 0);
  transpose_frag<<<dim3(NI / 64, NH / 64, NE), 256, 0, stream>>>(
      up, wcat, NH, NI, NI2 / 16, (long)NI2 * NH, 1, 16);
  transpose_frag<<<dim3(NH / 64, NI / 64, NE), 256, 0, stream>>>(
      down, dT, NI, NH, NH / 16, (long)NH * NI, 0, 0);

  // GEMM1: h = silu-pair(x @ wcat^T). 704 blocks @ 2/CU (1.375 rounds).
  gemm_frag<11, NH, 1><<<NE * 11 * 8, 256, 0, stream>>>(x_bf, wcat, hb);
  // GEMM2: out = h @ dT^T (f32). 512 blocks @ 2/CU = exactly 1.0 round.
  gemm_frag<8, NI, 0><<<NE * 8 * 8, 256, 0, stream>>>(hb, dT, out);
}

// Round 12
// 276.516 us; speedup vs baseline: 1.2735x; 1.2735x over previous
//
#include <hip/hip_runtime.h>
#include <hip/hip_bf16.h>
#include <stdint.h>

// Problem dims
#define NE 8
#define NT 1024
#define NH 2048
#define NI 1408
#define NI2 (2 * NI)  // 2816

typedef __attribute__((ext_vector_type(8))) short          bf16x8;
typedef __attribute__((ext_vector_type(8))) unsigned short u16x8;
typedef __attribute__((ext_vector_type(4))) float          f32x4;

__device__ __forceinline__ unsigned short f2bf(float f) {
  union { float f; uint32_t u; } v; v.f = f;
  uint32_t u = v.u;
  return (unsigned short)((u + 0x7FFFu + ((u >> 16) & 1u)) >> 16);  // RNE
}

// async global->LDS, 16B per lane. LDS dest is wave-uniform base + lane*16.
__device__ __forceinline__ void gload_lds16(const void* g, void* l) {
  __builtin_amdgcn_global_load_lds(
      (const __attribute__((address_space(1))) uint32_t*)g,
      (__attribute__((address_space(3))) uint32_t*)l, 16, 0, 0);
}

#define WAITV0() asm volatile("s_waitcnt vmcnt(0)" ::: "memory")
#define BAR() do { __builtin_amdgcn_sched_barrier(0); \
                   __builtin_amdgcn_s_barrier();      \
                   __builtin_amdgcn_sched_barrier(0); } while (0)

// ---------------------------------------------------------------------------
// x: fp32 -> bf16 elementwise
// ---------------------------------------------------------------------------
__global__ __launch_bounds__(256) void cvt_bf16(const float* __restrict__ src,
                                                unsigned short* __restrict__ dst,
                                                int n8) {
  int i = blockIdx.x * blockDim.x + threadIdx.x;
  const int stride = gridDim.x * blockDim.x;
  for (; i < n8; i += stride) {
    const float4 f0 = ((const float4*)src)[i * 2];
    const float4 f1 = ((const float4*)src)[i * 2 + 1];
    u16x8 o;
    o[0] = f2bf(f0.x); o[1] = f2bf(f0.y); o[2] = f2bf(f0.z); o[3] = f2bf(f0.w);
    o[4] = f2bf(f1.x); o[5] = f2bf(f1.y); o[6] = f2bf(f1.z); o[7] = f2bf(f1.w);
    ((u16x8*)dst)[i] = o;
  }
}

// ---------------------------------------------------------------------------
// Transpose + cvt:  src [E][R][C] f32  ->  dst rows mapped from c, ld = R, bf16
// ilv=1: out row = ((c>>4)<<5) | (c&15) | radd   (16-col gate/up interleave)
// 64x64 tile; float4 loads; 2 x 16B stores per thread.
// ---------------------------------------------------------------------------
__global__ __launch_bounds__(256) void transpose_cvt(
    const float* __restrict__ src, unsigned short* __restrict__ dst,
    int R, int C, long estride, int ilv, int radd) {
  __shared__ float tile[64][65];
  const int e  = blockIdx.z;
  const int c0 = blockIdx.x * 64;
  const int r0 = blockIdx.y * 64;
  const float* s = src + (size_t)e * R * C;
  unsigned short* d = dst + (size_t)e * estride;
  const int tid = threadIdx.x;
  const int tr  = tid >> 4;        // 0..15
  const int tc  = (tid & 15) * 4;  // 0..60
  #pragma unroll
  for (int it = 0; it < 4; ++it) {
    const int r = it * 16 + tr;
    float4 v = *(const float4*)(s + (size_t)(r0 + r) * C + c0 + tc);
    tile[r][tc + 0] = v.x; tile[r][tc + 1] = v.y;
    tile[r][tc + 2] = v.z; tile[r][tc + 3] = v.w;
  }
  __syncthreads();
  const int oc = tid >> 2;         // 0..63
  const int rb = (tid & 3) * 16;   // 0..48
  u16x8 o0, o1;
  #pragma unroll
  for (int j = 0; j < 8; ++j) {
    o0[j] = f2bf(tile[rb + j][oc]);
    o1[j] = f2bf(tile[rb + 8 + j][oc]);
  }
  const int c  = c0 + oc;
  const int ro = ilv ? ((((c >> 4) << 5) | (c & 15)) | radd) : c;
  unsigned short* dp = d + (size_t)ro * R + r0 + rb;
  *(u16x8*)dp       = o0;
  *(u16x8*)(dp + 8) = o1;
}

// ---------------------------------------------------------------------------
// GEMM1 (R8-proven): async minimal-sync, BM=BN=128, BK=64; 256 thr (4 waves
// 2Mx2N, wave tile 64x64). LDS 64 KB (2 bufs) -> 2 blocks/CU. ONE vmcnt(0)
// + BAR per K-tile (drains stage(t) issued one full iteration earlier).
// T2 XOR-swizzle via pre-swizzled global source; T1 XCD chunks.
// silu-pair bf16 out [E][1024][NBY*64] (B rows interleaved g16/u16)
// ---------------------------------------------------------------------------
template <int NBY, int KDIM>
__global__ __launch_bounds__(256, 2) void gemm_async(
    const unsigned short* __restrict__ Ag,  // [E][1024][KDIM]
    const unsigned short* __restrict__ Bg,  // [E][NBY*128][KDIM]
    unsigned short* __restrict__ outp) {
  constexpr int KT    = KDIM / 64;
  constexpr int CHUNK = NBY * 8;

  __shared__ __align__(16) unsigned short As[2][128 * 64];
  __shared__ __align__(16) unsigned short Bs[2][128 * 64];

  const int flat = blockIdx.x;
  const int orig = (flat & 7) * CHUNK + (flat >> 3);
  const int e    = orig / CHUNK;
  const int r    = orig % CHUNK;
  const int by   = r >> 3;
  const int bx   = r & 7;

  const int bm  = bx * 128;
  const int bnn = by * 128;

  const int tid  = threadIdx.x;
  const int lane = tid & 63;
  const int w    = tid >> 6;
  const int wrm  = (w >> 1) * 64;
  const int wcn  = (w & 1) * 64;

  const unsigned short* Ae = Ag + (size_t)e * 1024 * KDIM;
  const unsigned short* Be = Bg + (size_t)e * (NBY * 128) * KDIM;

  const int l8 = lane >> 3;
  const int jx = (lane & 7) ^ l8;
  const unsigned short* aA = Ae + (size_t)(bm  + w * 32 + l8) * KDIM + jx * 8;
  const unsigned short* aB = Be + (size_t)(bnn + w * 32 + l8) * KDIM + jx * 8;

  f32x4 acc[4][4];
  #pragma unroll
  for (int i = 0; i < 4; ++i)
    #pragma unroll
    for (int j = 0; j < 4; ++j) acc[i][j] = f32x4{0.f, 0.f, 0.f, 0.f};

  const int aoff = (lane & 15) * 128 + ((((lane >> 4) << 4)) ^ ((lane & 7) << 4));

  auto STAGE = [&](unsigned short* Ad, unsigned short* Bd, int t) {
    const int kb = t * 64;
    #pragma unroll
    for (int q = 0; q < 4; ++q)
      gload_lds16(aA + (size_t)q * 8 * KDIM + kb, Ad + (w * 32 + q * 8) * 64);
    #pragma unroll
    for (int q = 0; q < 4; ++q)
      gload_lds16(aB + (size_t)q * 8 * KDIM + kb, Bd + (w * 32 + q * 8) * 64);
  };

  auto ITER = [&](int t, const unsigned short* Ac, const unsigned short* Bc,
                  unsigned short* An, unsigned short* Bn) {
    WAITV0();
    BAR();
    const char* Ab = (const char*)Ac + wrm * 128;
    const char* Bb = (const char*)Bc + wcn * 128;
    bf16x8 a[4][2], b[4][2];
    #pragma unroll
    for (int mi = 0; mi < 4; ++mi) {
      a[mi][0] = *(const bf16x8*)(Ab + mi * 2048 + aoff);
      a[mi][1] = *(const bf16x8*)(Ab + mi * 2048 + (aoff ^ 64));
    }
    #pragma unroll
    for (int nj = 0; nj < 4; ++nj) {
      b[nj][0] = *(const bf16x8*)(Bb + nj * 2048 + aoff);
      b[nj][1] = *(const bf16x8*)(Bb + nj * 2048 + (aoff ^ 64));
    }
    if (t + 1 < KT) STAGE(An, Bn, t + 1);
    #pragma unroll
    for (int kk = 0; kk < 2; ++kk)
      #pragma unroll
      for (int mi = 0; mi < 4; ++mi)
        #pragma unroll
        for (int nj = 0; nj < 4; ++nj)
          acc[mi][nj] = __builtin_amdgcn_mfma_f32_16x16x32_bf16(
              a[mi][kk], b[nj][kk], acc[mi][nj], 0, 0, 0);
  };

  STAGE(As[0], Bs[0], 0);

  #pragma unroll 1
  for (int t = 0; t < KT; t += 2) {
    ITER(t,     As[0], Bs[0], As[1], Bs[1]);
    ITER(t + 1, As[1], Bs[1], As[0], Bs[0]);
  }

  const int crow = (lane >> 4) * 4;
  const int ccol = lane & 15;
  unsigned short* he = outp + (size_t)e * 1024 * (NBY * 64);
  const int hcb = by * 64 + (wcn >> 1);
  #pragma unroll
  for (int mi = 0; mi < 4; ++mi)
    #pragma unroll
    for (int p = 0; p < 2; ++p)
      #pragma unroll
      for (int j = 0; j < 4; ++j) {
        const float g = acc[mi][2 * p][j];
        const float u = acc[mi][2 * p + 1][j];
        const float sv = g / (1.0f + __expf(-g)) * u;
        const int row = bm + wrm + mi * 16 + crow + j;
        const int col = hcb + p * 16 + ccol;
        he[(size_t)row * (NBY * 64) + col] = f2bf(sv);
      }
}

// ---------------------------------------------------------------------------
// GEMM2 (R4-proven): 8-phase 256², BK=64, 512 thr (8 waves 2Mx4N, wave tile
// 128x64), 2 LDS buffers (128 KB), 4 phases/K-tile, stage issued P1/P2 and
// waited end-P4. f32 out. Grid 256 = exactly 1/CU.
// ---------------------------------------------------------------------------
template <int NBY, int KDIM>
__global__ __launch_bounds__(512, 2) void gemm_pipe8(
    const unsigned short* __restrict__ Ag,  // [E][1024][KDIM]
    const unsigned short* __restrict__ Bg,  // [E][NBY*256][KDIM]
    float* __restrict__ outp) {
  constexpr int KT    = KDIM / 64;
  constexpr int CHUNK = NBY * 4;

  __shared__ __align__(16) unsigned short As[2][256 * 64];
  __shared__ __align__(16) unsigned short Bs[2][256 * 64];

  const int flat = blockIdx.x;
  const int orig = (flat & 7) * CHUNK + (flat >> 3);
  const int bx   = orig & 3;
  const int by   = (orig >> 2) % NBY;
  const int e    = (orig >> 2) / NBY;

  const int bm  = bx * 256;
  const int bnn = by * 256;

  const int tid  = threadIdx.x;
  const int lane = tid & 63;
  const int w    = tid >> 6;
  const int wrm  = (w >> 2) * 128;
  const int wcn  = (w & 3) * 64;

  const unsigned short* Ae = Ag + (size_t)e * 1024 * KDIM;
  const unsigned short* Be = Bg + (size_t)e * (NBY * 256) * KDIM;

  const int l8 = lane >> 3;
  const int jx = (lane & 7) ^ l8;
  const unsigned short* aAg = Ae + (size_t)(bm  + w * 32 + l8) * KDIM + jx * 8;
  const unsigned short* aBg = Be + (size_t)(bnn + w * 32 + l8) * KDIM + jx * 8;

  f32x4 acc[8][4];
  #pragma unroll
  for (int i = 0; i < 8; ++i)
    #pragma unroll
    for (int j = 0; j < 4; ++j) acc[i][j] = f32x4{0.f, 0.f, 0.f, 0.f};

  const int aoff = (lane & 15) * 128 + ((((lane >> 4) << 4)) ^ ((lane & 7) << 4));

  auto STAGE_A = [&](unsigned short* dst, int t) {
    const unsigned short* g = aAg + (size_t)t * 64;
    #pragma unroll
    for (int q = 0; q < 4; ++q)
      gload_lds16(g + (size_t)q * 8 * KDIM, dst + (w * 32 + q * 8) * 64);
  };
  auto STAGE_B = [&](unsigned short* dst, int t) {
    const unsigned short* g = aBg + (size_t)t * 64;
    #pragma unroll
    for (int q = 0; q < 4; ++q)
      gload_lds16(g + (size_t)q * 8 * KDIM, dst + (w * 32 + q * 8) * 64);
  };

  unsigned short *Ac = As[0], *Bc = Bs[0], *An = As[1], *Bn = Bs[1];

  STAGE_A(Ac, 0);
  STAGE_B(Bc, 0);
  WAITV0();
  BAR();

  #pragma unroll 1
  for (int t = 0; t < KT; ++t) {
    const bool st = (t + 1 < KT);
    const char* Ab = (const char*)Ac + wrm * 128;
    const char* Bb = (const char*)Bc + wcn * 128;
    bf16x8 a0[4][2], a1[4][2], b0[2][2], b1[2][2];

    // ---- P1
    #pragma unroll
    for (int mi = 0; mi < 4; ++mi) {
      a0[mi][0] = *(const bf16x8*)(Ab + mi * 2048 + aoff);
      a0[mi][1] = *(const bf16x8*)(Ab + mi * 2048 + (aoff ^ 64));
    }
    #pragma unroll
    for (int nj = 0; nj < 2; ++nj) {
      b0[nj][0] = *(const bf16x8*)(Bb + nj * 2048 + aoff);
      b0[nj][1] = *(const bf16x8*)(Bb + nj * 2048 + (aoff ^ 64));
    }
    if (st) STAGE_A(An, t + 1);
    BAR();
    __builtin_amdgcn_s_setprio(1);
    #pragma unroll
    for (int kk = 0; kk < 2; ++kk)
      #pragma unroll
      for (int mi = 0; mi < 4; ++mi)
        #pragma unroll
        for (int nj = 0; nj < 2; ++nj)
          acc[mi][nj] = __builtin_amdgcn_mfma_f32_16x16x32_bf16(
              a0[mi][kk], b0[nj][kk], acc[mi][nj], 0, 0, 0);
    __builtin_amdgcn_s_setprio(0);
    BAR();

    // ---- P2
    #pragma unroll
    for (int nj = 0; nj < 2; ++nj) {
      b1[nj][0] = *(const bf16x8*)(Bb + (2 + nj) * 2048 + aoff);
      b1[nj][1] = *(const bf16x8*)(Bb + (2 + nj) * 2048 + (aoff ^ 64));
    }
    if (st) STAGE_B(Bn, t + 1);
    BAR();
    __builtin_amdgcn_s_setprio(1);
    #pragma unroll
    for (int kk = 0; kk < 2; ++kk)
      #pragma unroll
      for (int mi = 0; mi < 4; ++mi)
        #pragma unroll
        for (int nj = 0; nj < 2; ++nj)
          acc[mi][2 + nj] = __builtin_amdgcn_mfma_f32_16x16x32_bf16(
              a0[mi][kk], b1[nj][kk], acc[mi][2 + nj], 0, 0, 0);
    __builtin_amdgcn_s_setprio(0);
    BAR();

    // ---- P3
    #pragma unroll
    for (int mi = 0; mi < 4; ++mi) {
      a1[mi][0] = *(const bf16x8*)(Ab + 8192 + mi * 2048 + aoff);
      a1[mi][1] = *(const bf16x8*)(Ab + 8192 + mi * 2048 + (aoff ^ 64));
    }
    BAR();
    __builtin_amdgcn_s_setprio(1);
    #pragma unroll
    for (int kk = 0; kk < 2; ++kk)
      #pragma unroll
      for (int mi = 0; mi < 4; ++mi)
        #pragma unroll
        for (int nj = 0; nj < 2; ++nj)
          acc[4 + mi][2 + nj] = __builtin_amdgcn_mfma_f32_16x16x32_bf16(
              a1[mi][kk], b1[nj][kk], acc[4 + mi][2 + nj], 0, 0, 0);
    __builtin_amdgcn_s_setprio(0);
    BAR();

    // ---- P4
    __builtin_amdgcn_s_setprio(1);
    #pragma unroll
    for (int kk = 0; kk < 2; ++kk)
      #pragma unroll
      for (int mi = 0; mi < 4; ++mi)
        #pragma unroll
        for (int nj = 0; nj < 2; ++nj)
          acc[4 + mi][nj] = __builtin_amdgcn_mfma_f32_16x16x32_bf16(
              a1[mi][kk], b0[nj][kk], acc[4 + mi][nj], 0, 0, 0);
    __builtin_amdgcn_s_setprio(0);
    if (st) WAITV0();
    BAR();

    unsigned short* tp;
    tp = Ac; Ac = An; An = tp;
    tp = Bc; Bc = Bn; Bn = tp;
  }

  const int crow = (lane >> 4) * 4;
  const int ccol = lane & 15;
  float* oe = outp + (size_t)e * 1024 * (NBY * 256);
  #pragma unroll
  for (int mi = 0; mi < 8; ++mi)
    #pragma unroll
    for (int nj = 0; nj < 4; ++nj)
      #pragma unroll
      for (int j = 0; j < 4; ++j) {
        const int row = bm + wrm + mi * 16 + crow + j;
        const int col = bnn + wcn + nj * 16 + ccol;
        oe[(size_t)row * (NBY * 256) + col] = acc[mi][nj][j];
      }
}

// ---------------------------------------------------------------------------
extern "C" void kernel_launch(void* const* d_in, const int* in_sizes, int n_in,
                              void* d_out, int out_size, void* d_ws, size_t ws_size,
                              hipStream_t stream) {
  const float* x    = (const float*)d_in[0];  // [E][T][H]
  const float* gate = (const float*)d_in[1];  // [E][H][I]
  const float* up   = (const float*)d_in[2];  // [E][H][I]
  const float* down = (const float*)d_in[3];  // [E][I][H]
  float* out = (float*)d_out;                 // [E][T][H]

  // workspace (bf16): x_bf [E][T][H], wcat [E][2I][H] (g/u 16-col interleave),
  // dT [E][H][I], h [E][T][I].
  unsigned short* x_bf = (unsigned short*)d_ws;
  unsigned short* wcat = x_bf + (size_t)NE * NT * NH;
  unsigned short* dT   = wcat + (size_t)NE * NI2 * NH;
  unsigned short* hb   = dT   + (size_t)NE * NH * NI;

  cvt_bf16<<<2048, 256, 0, stream>>>(x, x_bf, NE * NT * NH / 8);

  transpose_cvt<<<dim3(NI / 64, NH / 64, NE), 256, 0, stream>>>(
      gate, wcat, NH, NI, (long)NI2 * NH, 1, 0);
  transpose_cvt<<<dim3(NI / 64, NH / 64, NE), 256, 0, stream>>>(
      up, wcat, NH, NI, (long)NI2 * NH, 1, 16);
  transpose_cvt<<<dim3(NH / 64, NI / 64, NE), 256, 0, stream>>>(
      down, dT, NI, NH, (long)NH * NI, 0, 0);

  // GEMM1 (R8): h = silu-pair(x_bf @ wcat^T). 1408 blocks @ 2/CU.
  gemm_async<22, NH><<<NE * 22 * 8, 256, 0, stream>>>(x_bf, wcat, hb);
  // GEMM2 (R4 8-phase): out = h @ dT^T (f32). 256 blocks = 1/CU exact.
  gemm_pipe8<8, NI><<<NE * 8 * 4, 512, 0, stream>>>(hb, dT, out);
}